// Round 4
// baseline (269.507 us; speedup 1.0000x reference)
//
#include <hip/hip_runtime.h>
#include <hip/hip_bf16.h>

#define TT      5
#define NHEADS  6
#define DIMC    192
#define SHIFT_  4
#define HDIM_   32
#define NTOK    320
#define NWIN    64
#define BATCH   2
#define LOG2E   1.44269504088896f
#define SCALE_LOG2E (0.17677669529663687f * 1.44269504088896f)
#define NEGMASK (-100.0f * 1.44269504088896f)

typedef short short8v __attribute__((ext_vector_type(8)));
typedef float floatx4 __attribute__((ext_vector_type(4)));
union FragU { uint4 u; short8v s; };

static __device__ __forceinline__ float bf16lo(unsigned u) {
    union { unsigned i; float f; } x; x.i = u << 16; return x.f;
}
static __device__ __forceinline__ float bf16hi(unsigned u) {
    union { unsigned i; float f; } x; x.i = u & 0xffff0000u; return x.f;
}
static __device__ __forceinline__ unsigned short bf16b(float f) {
    __hip_bfloat16 h = __float2bfloat16(f);
    unsigned short u; __builtin_memcpy(&u, &h, 2); return u;
}
static __device__ __forceinline__ unsigned pk2(float a, float b) {
    return (unsigned)bf16b(a) | ((unsigned)bf16b(b) << 16);
}
// fast half-up bf16 pair pack (P-matrix only: e >= 0, never NaN; <=1ulp bias,
// well inside tolerance). 5 VALU ops vs ~16 for the exact libcall pair.
static __device__ __forceinline__ unsigned pk2h(float a, float b) {
    unsigned ua = __float_as_uint(a), ub = __float_as_uint(b);
    return ((ua + 0x8000u) >> 16) | ((ub + 0x8000u) & 0xffff0000u);
}

// Runtime dtype sniffer (bf16-pair vs f32 data) — wave-uniform, deterministic.
static __device__ __forceinline__ bool detect_bf16(const unsigned* q) {
    uint4 w = ((const uint4*)q)[threadIdx.x & 63];
    int cnt = 0;
    unsigned e;
    e = (w.x >> 7) & 0xffu; cnt += (e >= 100u && e <= 135u);
    e = (w.y >> 7) & 0xffu; cnt += (e >= 100u && e <= 135u);
    e = (w.z >> 7) & 0xffu; cnt += (e >= 100u && e <= 135u);
    e = (w.w >> 7) & 0xffu; cnt += (e >= 100u && e <= 135u);
    unsigned long long m = __ballot(cnt >= 2);
    return __popcll(m) >= 32;
}

// ---------------------------------------------------------------------------
// Attention: 1 block per (window b_, head h). 5 waves x 64 queries.
// LDS 48.6 KB -> 3 blocks/CU; grid 768 = 256 CU x 3 = exactly one round.
// K-frags streamed from global with kt-granular ping-pong prefetch (no sK).
// S^T = K·Q^T via mfma_16x16x32_bf16; P round-trips LDS (A-layout); PV with
// B = V^T staged in LDS.
// ---------------------------------------------------------------------------
__global__ __launch_bounds__(NTOK, 4) void attn_mfma(
    const void* __restrict__ qkv_raw,
    const void* __restrict__ bias_raw,
    __hip_bfloat16* __restrict__ win_out)          // ws: [B_][320][192]
{
    const bool isbf = detect_bf16((const unsigned*)qkv_raw);
    const int b_  = blockIdx.x;       // 0..127
    const int h   = blockIdx.y;       // 0..5
    const int bb  = b_ >> 6;
    const int wdx = b_ & 63;
    const int wi  = wdx >> 3, wj = wdx & 7;
    const int tid = threadIdx.x;
    const int w    = tid >> 6;        // wave 0..4
    const int lane = tid & 63;
    const int l15  = lane & 15;
    const int quad = lane >> 4;       // 0..3

    __shared__ unsigned short sVT[32 * 328];   // V^T [dim][token]  (21.0 KB)
    __shared__ unsigned short sP[5 * 64 * 40]; // per-wave P [64 q][32 k] (25.6 KB)
    __shared__ float sBias[192];               // head's bias column * LOG2E
    __shared__ float sRS[320];                 // row sums

    // ---- staging: thread n = one token; V^T column + bias ----
    {
        const int n = tid;
        const int t = n >> 6, s = n & 63, hl = s >> 3, wl = s & 7;
        const int gh = (wi * 8 + hl + SHIFT_) & 63;
        const int gw = (wj * 8 + wl + SHIFT_) & 63;
        const long grow = (long)bb * (TT * 64 * 64) + t * 4096 + gh * 64 + gw;
        if (!isbf) {
            const float* vp = (const float*)qkv_raw + grow * (3 * DIMC) + 2 * DIMC + h * HDIM_;
            #pragma unroll
            for (int d = 0; d < 32; d++) sVT[d * 328 + n] = bf16b(vp[d]);
            if (tid < 192)
                sBias[tid] = ((const float*)bias_raw)[tid * NHEADS + h] * LOG2E;
        } else {
            const unsigned* vp = (const unsigned*)((const __hip_bfloat16*)qkv_raw + grow * (3 * DIMC) + 2 * DIMC + h * HDIM_);
            #pragma unroll
            for (int i = 0; i < 16; i++) {
                unsigned u = vp[i];
                sVT[(2*i+0) * 328 + n] = (unsigned short)(u & 0xffffu);
                sVT[(2*i+1) * 328 + n] = (unsigned short)(u >> 16);
            }
            if (tid < 192)
                sBias[tid] = __bfloat162float(((const __hip_bfloat16*)bias_raw)[tid * NHEADS + h]) * LOG2E;
        }
    }

    // ---- per-lane Q fragments (B-operand: n=query=l15, k=dim=quad*8+j) ----
    FragU qf[4];
    int cn_q[4], labq[4];
    #pragma unroll
    for (int jq = 0; jq < 4; jq++) {
        const int qtok = w * 64 + jq * 16 + l15;
        const int t = qtok >> 6, s = qtok & 63, hl = s >> 3, wl = s & 7;
        cn_q[jq] = t * 15 + hl + wl;
        const int hh = wi * 8 + hl, ww = wj * 8 + wl;
        labq[jq] = ((hh < 56) ? 0 : ((hh < 60) ? 1 : 2)) * 3 +
                   ((ww < 56) ? 0 : ((ww < 60) ? 1 : 2));
        const int gh = (wi * 8 + hl + SHIFT_) & 63;
        const int gw = (wj * 8 + wl + SHIFT_) & 63;
        const long grow = (long)bb * (TT * 64 * 64) + t * 4096 + gh * 64 + gw;
        if (!isbf) {
            const float* qp = (const float*)qkv_raw + grow * (3 * DIMC) + h * HDIM_ + quad * 8;
            qf[jq].u = make_uint4(
                pk2(qp[0]*SCALE_LOG2E, qp[1]*SCALE_LOG2E), pk2(qp[2]*SCALE_LOG2E, qp[3]*SCALE_LOG2E),
                pk2(qp[4]*SCALE_LOG2E, qp[5]*SCALE_LOG2E), pk2(qp[6]*SCALE_LOG2E, qp[7]*SCALE_LOG2E));
        } else {
            const uint4 uu = *(const uint4*)((const __hip_bfloat16*)qkv_raw + grow * (3 * DIMC) + h * HDIM_ + quad * 8);
            qf[jq].u = make_uint4(
                pk2(bf16lo(uu.x)*SCALE_LOG2E, bf16hi(uu.x)*SCALE_LOG2E),
                pk2(bf16lo(uu.y)*SCALE_LOG2E, bf16hi(uu.y)*SCALE_LOG2E),
                pk2(bf16lo(uu.z)*SCALE_LOG2E, bf16hi(uu.z)*SCALE_LOG2E),
                pk2(bf16lo(uu.w)*SCALE_LOG2E, bf16hi(uu.w)*SCALE_LOG2E));
        }
    }

    // K-chunk lane offset (16-token chunk m16; this lane covers token
    // m16*16+l15, dims quad*8..+7) — element offset into qkv.
    auto koff = [&](int m16) -> long {
        const int token = m16 * 16 + l15;
        const int t = token >> 6, s = token & 63, hl2 = s >> 3, wl2 = s & 7;
        const int gh2 = (wi * 8 + hl2 + SHIFT_) & 63;
        const int gw2 = (wj * 8 + wl2 + SHIFT_) & 63;
        return ((long)bb * (TT * 64 * 64) + t * 4096 + gh2 * 64 + gw2) * (3 * DIMC)
               + DIMC + h * HDIM_ + quad * 8;
    };
    auto loadKt = [&](uint4* d, int m16) {
        const long off = koff(m16);
        if (!isbf) {
            const uint4* p = (const uint4*)((const float*)qkv_raw + off);
            d[0] = p[0]; d[1] = p[1];
        } else {
            d[0] = *(const uint4*)((const __hip_bfloat16*)qkv_raw + off);
        }
    };
    auto cvtKt = [&](const uint4* d) -> FragU {
        FragU kf;
        if (!isbf) {
            const float* f = (const float*)d;
            kf.u = make_uint4(pk2(f[0], f[1]), pk2(f[2], f[3]),
                              pk2(f[4], f[5]), pk2(f[6], f[7]));
        } else kf.u = d[0];
        return kf;
    };

    uint4 rA[2], rB[2];
    loadKt(rA, 0);                      // prefetch chunk 0 across the barrier
    __syncthreads();

    unsigned short* sPw = &sP[w * 64 * 40];
    const floatx4 z4 = {0.f, 0.f, 0.f, 0.f};
    floatx4 oacc[4][2];
    #pragma unroll
    for (int i = 0; i < 4; i++) { oacc[i][0] = z4; oacc[i][1] = z4; }
    float rs[4] = {0.f, 0.f, 0.f, 0.f};

    // one kt half-step: 4 S-MFMAs, exp+bias+mask, pack, P-write
    auto do_kt = [&](int kb, int kt, const FragU& kf) {
        floatx4 sv[4];
        #pragma unroll
        for (int jq = 0; jq < 4; jq++)
            sv[jq] = __builtin_amdgcn_mfma_f32_16x16x32_bf16(kf.s, qf[jq].s, z4, 0, 0, 0);
        const int kbase = kb * 32 + kt * 16;
        const int Ck = (7 - (kbase >> 6)) * 15 + 7;
        const int sh = ((kbase & 63) >> 3) + (quad >> 1);
        const int rhk = (wi == 7) ? ((sh < 4) ? 1 : 2) : 0;
        int cjv[4], labk[4];
        #pragma unroll
        for (int reg = 0; reg < 4; reg++) {
            const int sw = (quad & 1) * 4 + reg;
            cjv[reg] = Ck - sh - sw;
            labk[reg] = rhk * 3 + ((wj == 7) ? ((sw < 4) ? 1 : 2) : 0);
        }
        #pragma unroll
        for (int jq = 0; jq < 4; jq++) {
            float e[4];
            #pragma unroll
            for (int reg = 0; reg < 4; reg++) {
                const float bv = sBias[cn_q[jq] + cjv[reg]];
                const float mv = (labk[reg] != labq[jq]) ? NEGMASK : 0.f;
                e[reg] = exp2f(sv[jq][reg] + bv + mv);
            }
            rs[jq] += (e[0] + e[1]) + (e[2] + e[3]);
            *(uint2*)&sPw[(jq * 16 + l15) * 40 + kt * 16 + quad * 4] =
                make_uint2(pk2h(e[0], e[1]), pk2h(e[2], e[3]));
        }
    };

    for (int kb = 0; kb < 10; kb++) {
        loadKt(rB, 2 * kb + 1);                   // in flight through kt0
        { FragU kf = cvtKt(rA); do_kt(kb, 0, kf); }
        if (kb < 9) loadKt(rA, 2 * kb + 2);       // in flight through kt1
        FragU vf0, vf1;
        vf0.u = *(const uint4*)&sVT[l15 * 328 + kb * 32 + quad * 8];
        vf1.u = *(const uint4*)&sVT[(16 + l15) * 328 + kb * 32 + quad * 8];
        { FragU kf = cvtKt(rB); do_kt(kb, 1, kf); }
        #pragma unroll
        for (int i = 0; i < 4; i++) {
            FragU pf; pf.u = *(const uint4*)&sPw[(i * 16 + l15) * 40 + quad * 8];
            oacc[i][0] = __builtin_amdgcn_mfma_f32_16x16x32_bf16(pf.s, vf0.s, oacc[i][0], 0, 0, 0);
            oacc[i][1] = __builtin_amdgcn_mfma_f32_16x16x32_bf16(pf.s, vf1.s, oacc[i][1], 0, 0, 0);
        }
    }

    // ---- row sums: reduce over quads, redistribute by row ----
    #pragma unroll
    for (int jq = 0; jq < 4; jq++) {
        float r = rs[jq];
        r += __shfl_xor(r, 16);
        r += __shfl_xor(r, 32);
        if (lane < 16) sRS[w * 64 + jq * 16 + lane] = r;
    }
    #pragma unroll
    for (int i = 0; i < 4; i++) {
        float inv[4];
        #pragma unroll
        for (int reg = 0; reg < 4; reg++)
            inv[reg] = 1.0f / sRS[w * 64 + i * 16 + quad * 4 + reg];
        #pragma unroll
        for (int nt = 0; nt < 2; nt++) {
            #pragma unroll
            for (int reg = 0; reg < 4; reg++) {
                const int q = w * 64 + i * 16 + quad * 4 + reg;
                win_out[((long)b_ * NTOK + q) * DIMC + h * HDIM_ + nt * 16 + l15] =
                    __float2bfloat16(oacc[i][nt][reg] * inv[reg]);
            }
        }
    }
}

// ---------------------------------------------------------------------------
// prep_w: one-time W -> bf16 and bias -> f32 into workspace.
// ---------------------------------------------------------------------------
__global__ __launch_bounds__(256) void prep_w(
    const void* __restrict__ w_raw, const void* __restrict__ b_raw,
    const unsigned* __restrict__ sniff,
    unsigned short* __restrict__ wbf, float* __restrict__ bf32)
{
    const bool isbf = detect_bf16(sniff);
    const int g = blockIdx.x * 256 + threadIdx.x;   // grid sized exactly 36864
    if (!isbf) wbf[g] = bf16b(((const float*)w_raw)[g]);
    else       wbf[g] = ((const unsigned short*)w_raw)[g];
    if (blockIdx.x == 0 && threadIdx.x < 192) {
        bf32[threadIdx.x] = isbf
            ? __bfloat162float(((const __hip_bfloat16*)b_raw)[threadIdx.x])
            : ((const float*)b_raw)[threadIdx.x];
    }
}

// ---------------------------------------------------------------------------
// Projection GEMM, zero LDS: M=64 tokens/block (4 waves x 16), N=192, K=192.
// B-frags from L1/L2-resident bf16 W' (73.7 KB, shared by all blocks).
// Store with window-reverse + roll-back addressing.
// ---------------------------------------------------------------------------
__global__ __launch_bounds__(256) void proj_mfma(
    const __hip_bfloat16* __restrict__ win,       // ws: [B_][320][192]
    const unsigned short* __restrict__ wbf,       // ws: [192][192] bf16
    const float* __restrict__ bf32,               // ws: [192] f32
    const unsigned* __restrict__ sniff,
    void* __restrict__ out_raw)                   // [B][T*64*64][192]
{
    const bool isbf = detect_bf16(sniff);
    const int tid  = threadIdx.x;
    const int w    = tid >> 6;
    const int lane = tid & 63;
    const int l15  = lane & 15;
    const int quad = lane >> 4;
    const int tok0 = blockIdx.x * 64 + w * 16;

    const floatx4 z4 = {0.f, 0.f, 0.f, 0.f};
    floatx4 acc[12];
    #pragma unroll
    for (int nt = 0; nt < 12; nt++) acc[nt] = z4;

    #pragma unroll
    for (int ks = 0; ks < 6; ks++) {
        FragU af;
        af.u = *(const uint4*)(win + ((long)tok0 + l15) * DIMC + ks * 32 + quad * 8);
        #pragma unroll
        for (int nt = 0; nt < 12; nt++) {
            FragU bf_;
            bf_.u = *(const uint4*)(wbf + (nt * 16 + l15) * DIMC + ks * 32 + quad * 8);
            acc[nt] = __builtin_amdgcn_mfma_f32_16x16x32_bf16(af.s, bf_.s, acc[nt], 0, 0, 0);
        }
    }

    long rowoff[4];
    #pragma unroll
    for (int reg = 0; reg < 4; reg++) {
        const int token = tok0 + quad * 4 + reg;
        const int bw = token / NTOK;
        const int nn = token - bw * NTOK;
        const int bb = bw >> 6, wdx = bw & 63, wi2 = wdx >> 3, wj2 = wdx & 7;
        const int t = nn >> 6, s2 = nn & 63, hl = s2 >> 3, wl = s2 & 7;
        const int gh = (wi2 * 8 + hl + SHIFT_) & 63;
        const int gw = (wj2 * 8 + wl + SHIFT_) & 63;
        rowoff[reg] = ((long)bb * (TT * 64 * 64) + t * 4096 + gh * 64 + gw) * DIMC;
    }
    #pragma unroll
    for (int nt = 0; nt < 12; nt++) {
        const int o = nt * 16 + l15;
        const float bias = bf32[o];
        #pragma unroll
        for (int reg = 0; reg < 4; reg++) {
            const float v = acc[nt][reg] + bias;
            if (!isbf) ((float*)out_raw)[rowoff[reg] + o] = v;
            else       ((__hip_bfloat16*)out_raw)[rowoff[reg] + o] = __float2bfloat16(v);
        }
    }
}

extern "C" void kernel_launch(void* const* d_in, const int* in_sizes, int n_in,
                              void* d_out, int out_size, void* d_ws, size_t ws_size,
                              hipStream_t stream)
{
    (void)in_sizes; (void)n_in; (void)out_size; (void)ws_size;
    const void* qkv        = d_in[0];
    const void* bias_table = d_in[1];
    const void* proj_w     = d_in[2];
    const void* proj_b     = d_in[3];

    __hip_bfloat16* win = (__hip_bfloat16*)d_ws;                         // 15,728,640 B
    unsigned short* wbf = (unsigned short*)((char*)d_ws + 15728640);     //     73,728 B
    float*          bfb = (float*)((char*)d_ws + 15802368);              //        768 B

    prep_w<<<dim3(144), 256, 0, stream>>>(proj_w, proj_b, (const unsigned*)qkv, wbf, bfb);
    attn_mfma<<<dim3(BATCH * NWIN, NHEADS), NTOK, 0, stream>>>(qkv, bias_table, win);
    proj_mfma<<<dim3(BATCH * NWIN * NTOK / 64), 256, 0, stream>>>(
        win, wbf, bfb, (const unsigned*)qkv, d_out);
}

// Round 6
// 236.691 us; speedup vs baseline: 1.1386x; 1.1386x over previous
//
#include <hip/hip_runtime.h>
#include <hip/hip_bf16.h>

#define TT      5
#define NHEADS  6
#define DIMC    192
#define SHIFT_  4
#define HDIM_   32
#define NTOK    320
#define NWIN    64
#define BATCH   2
#define LOG2E   1.44269504088896f
#define SCALE_LOG2E (0.17677669529663687f * 1.44269504088896f)
#define NEGMASK (-100.0f * 1.44269504088896f)

typedef short short8v __attribute__((ext_vector_type(8)));
typedef float floatx4 __attribute__((ext_vector_type(4)));
union FragU { uint4 u; short8v s; };

static __device__ __forceinline__ float bf16lo(unsigned u) {
    union { unsigned i; float f; } x; x.i = u << 16; return x.f;
}
static __device__ __forceinline__ float bf16hi(unsigned u) {
    union { unsigned i; float f; } x; x.i = u & 0xffff0000u; return x.f;
}
static __device__ __forceinline__ unsigned short bf16b(float f) {
    __hip_bfloat16 h = __float2bfloat16(f);
    unsigned short u; __builtin_memcpy(&u, &h, 2); return u;
}
static __device__ __forceinline__ unsigned pk2(float a, float b) {
    return (unsigned)bf16b(a) | ((unsigned)bf16b(b) << 16);
}
// fast half-up bf16 pair pack (P-matrix only: e >= 0, never NaN; <=1ulp bias)
static __device__ __forceinline__ unsigned pk2h(float a, float b) {
    unsigned ua = __float_as_uint(a), ub = __float_as_uint(b);
    return ((ua + 0x8000u) >> 16) | ((ub + 0x8000u) & 0xffff0000u);
}

// Runtime dtype sniffer (bf16-pair vs f32 data) — wave-uniform, deterministic.
static __device__ __forceinline__ bool detect_bf16(const unsigned* q) {
    uint4 w = ((const uint4*)q)[threadIdx.x & 63];
    int cnt = 0;
    unsigned e;
    e = (w.x >> 7) & 0xffu; cnt += (e >= 100u && e <= 135u);
    e = (w.y >> 7) & 0xffu; cnt += (e >= 100u && e <= 135u);
    e = (w.z >> 7) & 0xffu; cnt += (e >= 100u && e <= 135u);
    e = (w.w >> 7) & 0xffu; cnt += (e >= 100u && e <= 135u);
    unsigned long long m = __ballot(cnt >= 2);
    return __popcll(m) >= 32;
}

// ---------------------------------------------------------------------------
// Attention: 1 block per (window b_, head h). 5 waves x 64 queries.
// LDS 48.6 KB -> 3 blocks/CU; grid 768 = 256 CU x 3 = one clean round.
//
// KEY-SLOT PERMUTATION: K rows are staged so that within each 32-key block,
// logical key ℓ = q4*8 + kt*4 + reg sits at MFMA tile slot kt*16 + q4*4 + reg.
// After the two S^T = K·Q^T MFMAs (kt=0,1), lane (l15,quad) then holds
// exactly keys quad*8 + kt*4 + reg — the PV A-operand layout — so P is
// packed entirely in-register (no LDS round-trip, no shuffles; this fixes
// R5's source/target-kt shuffle bug). V^T, bias and mask index by logical
// key: sh=(kb&1)*4+quad, sw=kt*4+reg, tk=kb>>1.
// Plain launch_bounds(320): the min-waves arg (R4) forced 64-VGPR spill.
// ---------------------------------------------------------------------------
__global__ __launch_bounds__(NTOK) void attn_mfma(
    const void* __restrict__ qkv_raw,
    const void* __restrict__ bias_raw,
    __hip_bfloat16* __restrict__ win_out)          // ws: [B_][320][192]
{
    const bool isbf = detect_bf16((const unsigned*)qkv_raw);
    const int b_  = blockIdx.x;       // 0..127
    const int h   = blockIdx.y;       // 0..5
    const int bb  = b_ >> 6;
    const int wdx = b_ & 63;
    const int wi  = wdx >> 3, wj = wdx & 7;
    const int tid = threadIdx.x;
    const int w    = tid >> 6;        // wave 0..4
    const int lane = tid & 63;
    const int l15  = lane & 15;
    const int quad = lane >> 4;       // 0..3

    __shared__ unsigned short sK[320 * 40];    // K rows bf16 (slot-permuted), stride 40
    __shared__ unsigned short sVT[32 * 328];   // V^T [dim][token]
    __shared__ float sBias[192];               // head's bias column * LOG2E
    __shared__ float sRS[320];                 // row sums

    // ---- staging: thread n = one token -> K row (permuted slot) + V^T col ----
    {
        const int n = tid;
        const int t = n >> 6, s = n & 63, hl = s >> 3, wl = s & 7;
        const int gh = (wi * 8 + hl + SHIFT_) & 63;
        const int gw = (wj * 8 + wl + SHIFT_) & 63;
        const long grow = (long)bb * (TT * 64 * 64) + t * 4096 + gh * 64 + gw;
        // slot within 32-block: l32 = q4*8 + kt*4 + reg  ->  kt*16 + q4*4 + reg
        const int l32  = n & 31;
        const int slot = (n & ~31) + ((l32 & 4) << 2) + ((l32 >> 3) << 2) + (l32 & 3);
        if (!isbf) {
            const float* base = (const float*)qkv_raw + grow * (3 * DIMC);
            const float* kp = base + DIMC + h * HDIM_;
            uint4* dst = (uint4*)&sK[slot * 40];
            #pragma unroll
            for (int i = 0; i < 4; i++)
                dst[i] = make_uint4(pk2(kp[8*i+0], kp[8*i+1]), pk2(kp[8*i+2], kp[8*i+3]),
                                    pk2(kp[8*i+4], kp[8*i+5]), pk2(kp[8*i+6], kp[8*i+7]));
            const float* vp = base + 2 * DIMC + h * HDIM_;
            #pragma unroll
            for (int d = 0; d < 32; d++) sVT[d * 328 + n] = bf16b(vp[d]);
            if (tid < 192)
                sBias[tid] = ((const float*)bias_raw)[tid * NHEADS + h] * LOG2E;
        } else {
            const __hip_bfloat16* base = (const __hip_bfloat16*)qkv_raw + grow * (3 * DIMC);
            const uint4* kp = (const uint4*)(base + DIMC + h * HDIM_);
            uint4* dst = (uint4*)&sK[slot * 40];
            #pragma unroll
            for (int i = 0; i < 4; i++) dst[i] = kp[i];
            const unsigned* vp = (const unsigned*)(base + 2 * DIMC + h * HDIM_);
            #pragma unroll
            for (int i = 0; i < 16; i++) {
                unsigned u = vp[i];
                sVT[(2*i+0) * 328 + n] = (unsigned short)(u & 0xffffu);
                sVT[(2*i+1) * 328 + n] = (unsigned short)(u >> 16);
            }
            if (tid < 192)
                sBias[tid] = __bfloat162float(((const __hip_bfloat16*)bias_raw)[tid * NHEADS + h]) * LOG2E;
        }
    }

    // ---- per-lane Q fragments (B-operand: n=query=l15, k=dim=quad*8+j) ----
    FragU qf[4];
    int cn_q[4], labq[4];
    #pragma unroll
    for (int jq = 0; jq < 4; jq++) {
        const int qtok = w * 64 + jq * 16 + l15;
        const int t = qtok >> 6, s = qtok & 63, hl = s >> 3, wl = s & 7;
        cn_q[jq] = t * 15 + hl + wl;
        const int hh = wi * 8 + hl, ww = wj * 8 + wl;
        labq[jq] = ((hh < 56) ? 0 : ((hh < 60) ? 1 : 2)) * 3 +
                   ((ww < 56) ? 0 : ((ww < 60) ? 1 : 2));
        const int gh = (wi * 8 + hl + SHIFT_) & 63;
        const int gw = (wj * 8 + wl + SHIFT_) & 63;
        const long grow = (long)bb * (TT * 64 * 64) + t * 4096 + gh * 64 + gw;
        if (!isbf) {
            const float* qp = (const float*)qkv_raw + grow * (3 * DIMC) + h * HDIM_ + quad * 8;
            qf[jq].u = make_uint4(
                pk2(qp[0]*SCALE_LOG2E, qp[1]*SCALE_LOG2E), pk2(qp[2]*SCALE_LOG2E, qp[3]*SCALE_LOG2E),
                pk2(qp[4]*SCALE_LOG2E, qp[5]*SCALE_LOG2E), pk2(qp[6]*SCALE_LOG2E, qp[7]*SCALE_LOG2E));
        } else {
            const uint4 uu = *(const uint4*)((const __hip_bfloat16*)qkv_raw + grow * (3 * DIMC) + h * HDIM_ + quad * 8);
            qf[jq].u = make_uint4(
                pk2(bf16lo(uu.x)*SCALE_LOG2E, bf16hi(uu.x)*SCALE_LOG2E),
                pk2(bf16lo(uu.y)*SCALE_LOG2E, bf16hi(uu.y)*SCALE_LOG2E),
                pk2(bf16lo(uu.z)*SCALE_LOG2E, bf16hi(uu.z)*SCALE_LOG2E),
                pk2(bf16lo(uu.w)*SCALE_LOG2E, bf16hi(uu.w)*SCALE_LOG2E));
        }
    }
    __syncthreads();

    const floatx4 z4 = {0.f, 0.f, 0.f, 0.f};
    floatx4 oacc[4][2];
    #pragma unroll
    for (int i = 0; i < 4; i++) { oacc[i][0] = z4; oacc[i][1] = z4; }
    float rs[4] = {0.f, 0.f, 0.f, 0.f};

    for (int kb = 0; kb < 10; kb++) {
        FragU kf0, kf1, vf0, vf1;
        kf0.u = *(const uint4*)&sK[(kb * 32 + l15) * 40 + quad * 8];
        kf1.u = *(const uint4*)&sK[(kb * 32 + 16 + l15) * 40 + quad * 8];
        vf0.u = *(const uint4*)&sVT[l15 * 328 + kb * 32 + quad * 8];
        vf1.u = *(const uint4*)&sVT[(16 + l15) * 328 + kb * 32 + quad * 8];

        floatx4 sv0[4], sv1[4];
        #pragma unroll
        for (int jq = 0; jq < 4; jq++)
            sv0[jq] = __builtin_amdgcn_mfma_f32_16x16x32_bf16(kf0.s, qf[jq].s, z4, 0, 0, 0);
        #pragma unroll
        for (int jq = 0; jq < 4; jq++)
            sv1[jq] = __builtin_amdgcn_mfma_f32_16x16x32_bf16(kf1.s, qf[jq].s, z4, 0, 0, 0);

        // logical key for (kt, reg) at this lane: kb*32 + quad*8 + kt*4 + reg
        const int Ck   = (7 - (kb >> 1)) * 15 + 7;
        const int sh   = (kb & 1) * 4 + quad;
        const int rhk  = (wi == 7) ? ((sh < 4) ? 1 : 2) : 0;
        const int lab0 = rhk * 3 + ((wj == 7) ? 1 : 0);   // kt0: sw=reg<4
        const int lab1 = rhk * 3 + ((wj == 7) ? 2 : 0);   // kt1: sw=4+reg
        const int cb   = Ck - sh;

        #pragma unroll
        for (int jq = 0; jq < 4; jq++) {
            const int bidx = cn_q[jq] + cb;
            const float m0 = (lab0 != labq[jq]) ? NEGMASK : 0.f;
            const float m1 = (lab1 != labq[jq]) ? NEGMASK : 0.f;
            float e0[4], e1[4];
            #pragma unroll
            for (int reg = 0; reg < 4; reg++)
                e0[reg] = exp2f(sv0[jq][reg] + sBias[bidx - reg] + m0);
            #pragma unroll
            for (int reg = 0; reg < 4; reg++)
                e1[reg] = exp2f(sv1[jq][reg] + sBias[bidx - 4 - reg] + m1);
            rs[jq] += ((e0[0] + e0[1]) + (e0[2] + e0[3]))
                    + ((e1[0] + e1[1]) + (e1[2] + e1[3]));
            FragU pf;
            pf.u.x = pk2h(e0[0], e0[1]); pf.u.y = pk2h(e0[2], e0[3]);
            pf.u.z = pk2h(e1[0], e1[1]); pf.u.w = pk2h(e1[2], e1[3]);
            oacc[jq][0] = __builtin_amdgcn_mfma_f32_16x16x32_bf16(pf.s, vf0.s, oacc[jq][0], 0, 0, 0);
            oacc[jq][1] = __builtin_amdgcn_mfma_f32_16x16x32_bf16(pf.s, vf1.s, oacc[jq][1], 0, 0, 0);
        }
    }

    // ---- row sums: reduce over quads, redistribute by row ----
    #pragma unroll
    for (int jq = 0; jq < 4; jq++) {
        float r = rs[jq];
        r += __shfl_xor(r, 16);
        r += __shfl_xor(r, 32);
        if (lane < 16) sRS[w * 64 + jq * 16 + lane] = r;
    }
    #pragma unroll
    for (int i = 0; i < 4; i++) {
        float inv[4];
        #pragma unroll
        for (int reg = 0; reg < 4; reg++)
            inv[reg] = 1.0f / sRS[w * 64 + i * 16 + quad * 4 + reg];
        #pragma unroll
        for (int nt = 0; nt < 2; nt++) {
            #pragma unroll
            for (int reg = 0; reg < 4; reg++) {
                const int q = w * 64 + i * 16 + quad * 4 + reg;
                win_out[((long)b_ * NTOK + q) * DIMC + h * HDIM_ + nt * 16 + l15] =
                    __float2bfloat16(oacc[i][nt][reg] * inv[reg]);
            }
        }
    }
}

// ---------------------------------------------------------------------------
// prep_w: one-time W -> bf16 and bias -> f32 into workspace.
// ---------------------------------------------------------------------------
__global__ __launch_bounds__(256) void prep_w(
    const void* __restrict__ w_raw, const void* __restrict__ b_raw,
    const unsigned* __restrict__ sniff,
    unsigned short* __restrict__ wbf, float* __restrict__ bf32)
{
    const bool isbf = detect_bf16(sniff);
    const int g = blockIdx.x * 256 + threadIdx.x;   // grid sized exactly 36864
    if (!isbf) wbf[g] = bf16b(((const float*)w_raw)[g]);
    else       wbf[g] = ((const unsigned short*)w_raw)[g];
    if (blockIdx.x == 0 && threadIdx.x < 192) {
        bf32[threadIdx.x] = isbf
            ? __bfloat162float(((const __hip_bfloat16*)b_raw)[threadIdx.x])
            : ((const float*)b_raw)[threadIdx.x];
    }
}

// ---------------------------------------------------------------------------
// Projection GEMM, zero LDS: M=64 tokens/block (4 waves x 16), N=192, K=192.
// B-frags from L1/L2-resident bf16 W' (73.7 KB, shared by all blocks).
// ---------------------------------------------------------------------------
__global__ __launch_bounds__(256) void proj_mfma(
    const __hip_bfloat16* __restrict__ win,       // ws: [B_][320][192]
    const unsigned short* __restrict__ wbf,       // ws: [192][192] bf16
    const float* __restrict__ bf32,               // ws: [192] f32
    const unsigned* __restrict__ sniff,
    void* __restrict__ out_raw)                   // [B][T*64*64][192]
{
    const bool isbf = detect_bf16(sniff);
    const int tid  = threadIdx.x;
    const int w    = tid >> 6;
    const int lane = tid & 63;
    const int l15  = lane & 15;
    const int quad = lane >> 4;
    const int tok0 = blockIdx.x * 64 + w * 16;

    const floatx4 z4 = {0.f, 0.f, 0.f, 0.f};
    floatx4 acc[12];
    #pragma unroll
    for (int nt = 0; nt < 12; nt++) acc[nt] = z4;

    #pragma unroll
    for (int ks = 0; ks < 6; ks++) {
        FragU af;
        af.u = *(const uint4*)(win + ((long)tok0 + l15) * DIMC + ks * 32 + quad * 8);
        #pragma unroll
        for (int nt = 0; nt < 12; nt++) {
            FragU bf_;
            bf_.u = *(const uint4*)(wbf + (nt * 16 + l15) * DIMC + ks * 32 + quad * 8);
            acc[nt] = __builtin_amdgcn_mfma_f32_16x16x32_bf16(af.s, bf_.s, acc[nt], 0, 0, 0);
        }
    }

    long rowoff[4];
    #pragma unroll
    for (int reg = 0; reg < 4; reg++) {
        const int token = tok0 + quad * 4 + reg;
        const int bw = token / NTOK;
        const int nn = token - bw * NTOK;
        const int bb = bw >> 6, wdx = bw & 63, wi2 = wdx >> 3, wj2 = wdx & 7;
        const int t = nn >> 6, s2 = nn & 63, hl = s2 >> 3, wl = s2 & 7;
        const int gh = (wi2 * 8 + hl + SHIFT_) & 63;
        const int gw = (wj2 * 8 + wl + SHIFT_) & 63;
        rowoff[reg] = ((long)bb * (TT * 64 * 64) + t * 4096 + gh * 64 + gw) * DIMC;
    }
    #pragma unroll
    for (int nt = 0; nt < 12; nt++) {
        const int o = nt * 16 + l15;
        const float bias = bf32[o];
        #pragma unroll
        for (int reg = 0; reg < 4; reg++) {
            const float v = acc[nt][reg] + bias;
            if (!isbf) ((float*)out_raw)[rowoff[reg] + o] = v;
            else       ((__hip_bfloat16*)out_raw)[rowoff[reg] + o] = __float2bfloat16(v);
        }
    }
}

extern "C" void kernel_launch(void* const* d_in, const int* in_sizes, int n_in,
                              void* d_out, int out_size, void* d_ws, size_t ws_size,
                              hipStream_t stream)
{
    (void)in_sizes; (void)n_in; (void)out_size; (void)ws_size;
    const void* qkv        = d_in[0];
    const void* bias_table = d_in[1];
    const void* proj_w     = d_in[2];
    const void* proj_b     = d_in[3];

    __hip_bfloat16* win = (__hip_bfloat16*)d_ws;                         // 15,728,640 B
    unsigned short* wbf = (unsigned short*)((char*)d_ws + 15728640);     //     73,728 B
    float*          bfb = (float*)((char*)d_ws + 15802368);              //        768 B

    prep_w<<<dim3(144), 256, 0, stream>>>(proj_w, proj_b, (const unsigned*)qkv, wbf, bfb);
    attn_mfma<<<dim3(BATCH * NWIN, NHEADS), NTOK, 0, stream>>>(qkv, bias_table, win);
    proj_mfma<<<dim3(BATCH * NWIN * NTOK / 64), 256, 0, stream>>>(
        win, wbf, bfb, (const unsigned*)qkv, d_out);
}